// Round 4
// baseline (1423.936 us; speedup 1.0000x reference)
//
#include <hip/hip_runtime.h>
#include <hip/hip_bf16.h>
#include <cstdint>
#include <cstddef>

#define B_    512
#define HW_   196
#define ENC_  2048
#define DEC_  512
#define ATTN_ 512
#define M_    (B_*HW_)   // 100352

typedef __attribute__((ext_vector_type(8))) short short8;
typedef __attribute__((ext_vector_type(4))) float f32x4;

// hardware RNE f32->bf16 (compiler emits v_cvt_pk_bf16_f32 on gfx950)
__device__ __forceinline__ unsigned short f2bf(float x) {
  __bf16 b = (__bf16)x;
  return __builtin_bit_cast(unsigned short, b);
}
__device__ __forceinline__ unsigned int cvt2(float x, float y) {
  return (unsigned)f2bf(x) | ((unsigned)f2bf(y) << 16);
}

// ---------------- kernel 1: attn2p[b][a] = dec_h[b]·W_dec[:,a] + b_dec[a] + b_enc[a]
__global__ __launch_bounds__(256)
void k_attn2(const float* __restrict__ dec_h, const float* __restrict__ Wdec,
             const float* __restrict__ bdec, const float* __restrict__ benc,
             float* __restrict__ attn2p) {
  __shared__ float dh[DEC_];
  const int b = blockIdx.x;
  const int t = threadIdx.x;
  dh[t]       = dec_h[b*DEC_ + t];
  dh[t + 256] = dec_h[b*DEC_ + t + 256];
  __syncthreads();
  #pragma unroll
  for (int rep = 0; rep < 2; ++rep) {
    const int a = t + rep*256;
    float acc = bdec[a] + benc[a];
    #pragma unroll 8
    for (int k = 0; k < DEC_; ++k)
      acc = fmaf(dh[k], Wdec[(size_t)k*ATTN_ + a], acc);
    attn2p[(size_t)b*ATTN_ + a] = acc;
  }
}

// ---------------- kernel 2: W_encT[a][e] = bf16(W_enc[e][a])
__global__ __launch_bounds__(256)
void k_transpose(const float* __restrict__ Wenc, unsigned short* __restrict__ WencT) {
  __shared__ float tile[32][33];
  const int e0 = blockIdx.x * 32;
  const int a0 = blockIdx.y * 32;
  const int t  = threadIdx.x;
  const int li = t >> 5;
  const int lj = t & 31;
  #pragma unroll
  for (int rep = 0; rep < 4; ++rep) {
    const int i = li + rep*8;
    tile[i][lj] = Wenc[(size_t)(e0 + i)*ATTN_ + a0 + lj];
  }
  __syncthreads();
  #pragma unroll
  for (int rep = 0; rep < 4; ++rep) {
    const int ar = li + rep*8;
    WencT[(size_t)(a0 + ar)*ENC_ + e0 + lj] = f2bf(tile[lj][ar]);
  }
}

// ---------------- kernel 3: barrier-free fused GEMM + bias + relu + dot(W_v)
// 1568 blocks x 512 threads (8 waves). Block = 64 rows x 512 cols (ALL of ATTN).
// Wave = 64x64 sub-tile: 4 m-frags x 4 n-frags of 16x16x32, acc = 64 VGPR.
// A (enc, f32): loaded DIRECT global->reg per MFMA-fragment layout (coalesced
//   128B/row), cvt_pk->bf16 in regs. 8 waves share the 8KB A-slice via L1.
// B (WencT bf16, 2MB, L2-resident): direct global->reg, wave-exclusive cols.
// NO LDS, NO barriers in the K-loop -> compiler emits counted vmcnt waits and
// the dist-1 prefetch (unroll-2, two named reg sets) stays in flight.
#define BK 32
#define NT (ENC_/BK)    // 64

__global__ __launch_bounds__(512, 2)
void k_gemm_logits(const float* __restrict__ enc,
                   const unsigned short* __restrict__ WencT,
                   const float* __restrict__ attn2p,
                   const float* __restrict__ Wv,
                   float* __restrict__ logits) {
  __shared__ float plog[64][8];

  const int tid = threadIdx.x;
  const int w   = tid >> 6;        // wave 0..7
  const int l   = tid & 63;
  const int lrow = l & 15;
  const int kg   = l >> 4;         // 0..3
  const int r0  = blockIdx.x * 64;
  const int n0w = w * 64;

  // per-lane fragment base pointers
  const float* aP[4];
  const unsigned short* bP[4];
  #pragma unroll
  for (int mi = 0; mi < 4; ++mi)
    aP[mi] = enc + (size_t)(r0 + mi*16 + lrow)*ENC_ + kg*8;
  #pragma unroll
  for (int nf = 0; nf < 4; ++nf)
    bP[nf] = WencT + (size_t)(n0w + nf*16 + lrow)*ENC_ + kg*8;

  f32x4 acc[4][4];
  #pragma unroll
  for (int mi = 0; mi < 4; ++mi)
    #pragma unroll
    for (int nf = 0; nf < 4; ++nf)
      acc[mi][nf] = (f32x4){0.f, 0.f, 0.f, 0.f};

  float4 Xa[4][2]; uint4 Xb[4];   // set X
  float4 Ya[4][2]; uint4 Yb[4];   // set Y

#define PREF(Sa, Sb, KT) do {                                        \
    const int _ko = (KT)*BK;                                         \
    _Pragma("unroll")                                                \
    for (int mi = 0; mi < 4; ++mi) {                                 \
      const float* _p = aP[mi] + _ko;                                \
      Sa[mi][0] = *reinterpret_cast<const float4*>(_p);              \
      Sa[mi][1] = *reinterpret_cast<const float4*>(_p + 4);          \
    }                                                                \
    _Pragma("unroll")                                                \
    for (int nf = 0; nf < 4; ++nf)                                   \
      Sb[nf] = *reinterpret_cast<const uint4*>(bP[nf] + _ko);        \
  } while (0)

#define COMP(Sa, Sb) do {                                            \
    short8 aC[4];                                                    \
    _Pragma("unroll")                                                \
    for (int mi = 0; mi < 4; ++mi) {                                 \
      uint4 pk;                                                      \
      pk.x = cvt2(Sa[mi][0].x, Sa[mi][0].y);                         \
      pk.y = cvt2(Sa[mi][0].z, Sa[mi][0].w);                         \
      pk.z = cvt2(Sa[mi][1].x, Sa[mi][1].y);                         \
      pk.w = cvt2(Sa[mi][1].z, Sa[mi][1].w);                         \
      aC[mi] = __builtin_bit_cast(short8, pk);                       \
    }                                                                \
    _Pragma("unroll")                                                \
    for (int mi = 0; mi < 4; ++mi)                                   \
      _Pragma("unroll")                                              \
      for (int nf = 0; nf < 4; ++nf)                                 \
        acc[mi][nf] = __builtin_amdgcn_mfma_f32_16x16x32_bf16(       \
            aC[mi], __builtin_bit_cast(short8, Sb[nf]),              \
            acc[mi][nf], 0, 0, 0);                                   \
  } while (0)

  PREF(Xa, Xb, 0);
  for (int kt = 0; kt < NT; kt += 2) {
    PREF(Ya, Yb, kt + 1);
    COMP(Xa, Xb);
    if (kt + 2 < NT) PREF(Xa, Xb, kt + 2);
    COMP(Ya, Yb);
  }
#undef PREF
#undef COMP

  // ---- epilogue: relu(acc + attn2p) · W_v over this wave's 64 cols
  float wvv[4], a2A[4], a2B[4];
  const int bbA = r0 / HW_;
  const int bbB = (r0 + 63) / HW_;
  #pragma unroll
  for (int nf = 0; nf < 4; ++nf) {
    const int col = n0w + nf*16 + lrow;
    wvv[nf] = Wv[col];
    a2A[nf] = attn2p[(size_t)bbA*ATTN_ + col];
    a2B[nf] = attn2p[(size_t)bbB*ATTN_ + col];
  }
  #pragma unroll
  for (int mi = 0; mi < 4; ++mi) {
    #pragma unroll
    for (int j = 0; j < 4; ++j) {
      const int rl = mi*16 + kg*4 + j;             // local row 0..63
      const int bb = (r0 + rl) / HW_;
      const bool useB = (bb != bbA);
      float s = 0.f;
      #pragma unroll
      for (int nf = 0; nf < 4; ++nf) {
        const float a2 = useB ? a2B[nf] : a2A[nf];
        const float v  = fmaxf(acc[mi][nf][j] + a2, 0.f);
        s = fmaf(v, wvv[nf], s);
      }
      s += __shfl_xor(s, 1);
      s += __shfl_xor(s, 2);
      s += __shfl_xor(s, 4);
      s += __shfl_xor(s, 8);
      if (lrow == 0) plog[rl][w] = s;
    }
  }
  __syncthreads();
  if (tid < 64) {
    float t = 0.f;
    #pragma unroll
    for (int ww = 0; ww < 8; ++ww) t += plog[tid][ww];
    logits[r0 + tid] = t;
  }
}

// ---------------- kernel 4: softmax over s (196) per b
__global__ __launch_bounds__(64)
void k_softmax(const float* __restrict__ logits, const float* __restrict__ bvp,
               float* __restrict__ alpha) {
  const int b = blockIdx.x;
  const int t = threadIdx.x;
  const float bv = bvp[0];
  float lg[4];
  #pragma unroll
  for (int i = 0; i < 4; ++i) {
    const int s = t + i*64;
    lg[i] = (s < HW_) ? (logits[b*HW_ + s] + bv) : -INFINITY;
  }
  float mx = fmaxf(fmaxf(lg[0], lg[1]), fmaxf(lg[2], lg[3]));
  #pragma unroll
  for (int off = 32; off; off >>= 1) mx = fmaxf(mx, __shfl_xor(mx, off));
  float sum = 0.f;
  #pragma unroll
  for (int i = 0; i < 4; ++i) { lg[i] = expf(lg[i] - mx); sum += lg[i]; }
  #pragma unroll
  for (int off = 32; off; off >>= 1) sum += __shfl_xor(sum, off);
  const float inv = 1.0f / sum;
  #pragma unroll
  for (int i = 0; i < 4; ++i) {
    const int s = t + i*64;
    if (s < HW_) alpha[b*HW_ + s] = lg[i] * inv;
  }
}

// ---------------- kernel 5: context[b][e] = sum_s alpha[b][s] * enc[b][s][e]
__global__ __launch_bounds__(256)
void k_context(const float* __restrict__ enc, const float* __restrict__ alpha,
               float* __restrict__ ctx) {
  __shared__ float al[HW_];
  const int bi = blockIdx.x;
  const int b  = bi >> 1;
  const int e0 = (bi & 1) << 10;
  const int t  = threadIdx.x;
  if (t < HW_) al[t] = alpha[b*HW_ + t];
  __syncthreads();
  const float* base = enc + (size_t)b*HW_*ENC_ + e0 + t*4;
  float4 acc = {0.f, 0.f, 0.f, 0.f};
  #pragma unroll 4
  for (int s = 0; s < HW_; ++s) {
    const float a = al[s];
    const float4 v = *reinterpret_cast<const float4*>(base + (size_t)s*ENC_);
    acc.x = fmaf(a, v.x, acc.x);
    acc.y = fmaf(a, v.y, acc.y);
    acc.z = fmaf(a, v.z, acc.z);
    acc.w = fmaf(a, v.w, acc.w);
  }
  *reinterpret_cast<float4*>(&ctx[(size_t)b*ENC_ + e0 + t*4]) = acc;
}

// ---------------- launch
extern "C" void kernel_launch(void* const* d_in, const int* in_sizes, int n_in,
                              void* d_out, int out_size, void* d_ws, size_t ws_size,
                              hipStream_t stream) {
  const float* enc   = (const float*)d_in[0];
  const float* dec_h = (const float*)d_in[1];
  const float* Wenc  = (const float*)d_in[2];
  const float* benc  = (const float*)d_in[3];
  const float* Wdec  = (const float*)d_in[4];
  const float* bdec  = (const float*)d_in[5];
  const float* Wv    = (const float*)d_in[6];
  const float* bv    = (const float*)d_in[7];

  float* ctx   = (float*)d_out;                     // [512][2048]
  float* alpha = (float*)d_out + (size_t)B_*ENC_;   // [512][196]

  char* ws = (char*)d_ws;
  float*          attn2p = (float*)ws;                          // 1.0 MB
  unsigned short* WencT  = (unsigned short*)(ws + (1u << 20));  // 2.0 MB
  float*          logits = (float*)(ws + 3u*(1u << 20));        // 0.4 MB [M]

  hipLaunchKernelGGL(k_attn2,     dim3(B_),                dim3(256), 0, stream,
                     dec_h, Wdec, bdec, benc, attn2p);
  hipLaunchKernelGGL(k_transpose, dim3(ENC_/32, ATTN_/32), dim3(256), 0, stream,
                     Wenc, WencT);
  hipLaunchKernelGGL(k_gemm_logits, dim3(M_/64),           dim3(512), 0, stream,
                     enc, WencT, attn2p, Wv, logits);
  hipLaunchKernelGGL(k_softmax,   dim3(B_),                dim3(64),  0, stream,
                     logits, bv, alpha);
  hipLaunchKernelGGL(k_context,   dim3(1024),              dim3(256), 0, stream,
                     enc, alpha, ctx);
}

// Round 5
// 738.494 us; speedup vs baseline: 1.9282x; 1.9282x over previous
//
#include <hip/hip_runtime.h>
#include <hip/hip_bf16.h>
#include <cstdint>
#include <cstddef>

#define B_    512
#define HW_   196
#define ENC_  2048
#define DEC_  512
#define ATTN_ 512
#define M_    (B_*HW_)   // 100352

typedef __attribute__((ext_vector_type(8))) short short8;
typedef __attribute__((ext_vector_type(4))) float f32x4;

// hardware RNE f32->bf16 (compiler emits v_cvt_pk_bf16_f32 on gfx950)
__device__ __forceinline__ unsigned short f2bf(float x) {
  __bf16 b = (__bf16)x;
  return __builtin_bit_cast(unsigned short, b);
}
__device__ __forceinline__ unsigned int cvt2(float x, float y) {
  return (unsigned)f2bf(x) | ((unsigned)f2bf(y) << 16);
}

__device__ __forceinline__ void gload_lds16(const void* g, void* l) {
  __builtin_amdgcn_global_load_lds(
      (const __attribute__((address_space(1))) void*)g,
      (__attribute__((address_space(3))) void*)l, 16, 0, 0);
}

// inverse of p = c ^ ((c>>2)&7)  (16B-chunk swizzle for the B tile)
__device__ __forceinline__ int invswz8(int p) {
  const int b2 = ((p >> 2) ^ (p >> 4)) & 1;
  const int b1 = ((p >> 1) ^ (p >> 3)) & 1;
  const int b0 = (p ^ (p >> 2) ^ (p >> 4)) & 1;
  return (p & ~7) | (b2 << 2) | (b1 << 1) | b0;
}

// ---------------- kernel 1: attn2p[b][a] = dec_h[b]·W_dec[:,a] + b_dec[a] + b_enc[a]
__global__ __launch_bounds__(256)
void k_attn2(const float* __restrict__ dec_h, const float* __restrict__ Wdec,
             const float* __restrict__ bdec, const float* __restrict__ benc,
             float* __restrict__ attn2p) {
  __shared__ float dh[DEC_];
  const int b = blockIdx.x;
  const int t = threadIdx.x;
  dh[t]       = dec_h[b*DEC_ + t];
  dh[t + 256] = dec_h[b*DEC_ + t + 256];
  __syncthreads();
  #pragma unroll
  for (int rep = 0; rep < 2; ++rep) {
    const int a = t + rep*256;
    float acc = bdec[a] + benc[a];
    #pragma unroll 8
    for (int k = 0; k < DEC_; ++k)
      acc = fmaf(dh[k], Wdec[(size_t)k*ATTN_ + a], acc);
    attn2p[(size_t)b*ATTN_ + a] = acc;
  }
}

// ---------------- kernel 2: W_encT[a][e] = bf16(W_enc[e][a])
__global__ __launch_bounds__(256)
void k_transpose(const float* __restrict__ Wenc, unsigned short* __restrict__ WencT) {
  __shared__ float tile[32][33];
  const int e0 = blockIdx.x * 32;
  const int a0 = blockIdx.y * 32;
  const int t  = threadIdx.x;
  const int li = t >> 5;
  const int lj = t & 31;
  #pragma unroll
  for (int rep = 0; rep < 4; ++rep) {
    const int i = li + rep*8;
    tile[i][lj] = Wenc[(size_t)(e0 + i)*ATTN_ + a0 + lj];
  }
  __syncthreads();
  #pragma unroll
  for (int rep = 0; rep < 4; ++rep) {
    const int ar = li + rep*8;
    WencT[(size_t)(a0 + ar)*ENC_ + e0 + lj] = f2bf(tile[lj][ar]);
  }
}

// ---------------- kernel 3: fused GEMM + bias + relu + dot(W_v) -> partial logits
// Single raw s_barrier per K-step with COUNTED vmcnt (T4): loads never drained.
// A (f32): global->reg dist-2 prefetch, cvt_pk->bf16, ds_write; As double-buffered.
// B (bf16): global_load_lds w16 dist-2, TRIPLE-buffered (safe vs 1-phase wave skew
//   because DMA-issue is post-barrier), source-side chunk swizzle (m173).
#define BM 128
#define BN 128
#define BK 32
#define LDA 40
#define NT (ENC_/BK)    // 64

__global__ __launch_bounds__(256)
void k_gemm_logits(const float* __restrict__ enc,
                   const unsigned short* __restrict__ WencT,
                   const float* __restrict__ attn2p,
                   const float* __restrict__ Wv,
                   float* __restrict__ partials) {
  __shared__ unsigned short As[2][BM*LDA];   // 2 x 10 KB
  __shared__ unsigned short Bs[3][BN*BK];    // 3 x 8 KB
  __shared__ float plog[BM][2];

  const int tid  = threadIdx.x;
  const int id   = blockIdx.x;
  const int xcd  = id & 7;
  const int rest = id >> 3;
  const int nb   = rest & 3;
  const int mblk = (rest >> 2) * 8 + xcd;   // 784 = 98*8, bijective; n-siblings share XCD
  const int r0 = mblk * BM;
  const int n0 = nb * BN;

  const int arow  = tid >> 1;
  const int ahalf = (tid & 1) << 4;
  const float* aptr = enc + (size_t)(r0 + arow)*ENC_ + ahalf;

  const unsigned short* bbase = WencT + (size_t)n0*ENC_;

  const int w  = tid >> 6;
  const int l  = tid & 63;
  const int wm = w >> 1, wn = w & 1;
  const int lrow = l & 15;
  const int kg   = l >> 4;
  const int lk8  = kg << 3;
  const int g4   = kg << 2;

  f32x4 acc[4][4];
  #pragma unroll
  for (int mi = 0; mi < 4; ++mi)
    #pragma unroll
    for (int ni = 0; ni < 4; ++ni)
      acc[mi][ni] = (f32x4){0.f, 0.f, 0.f, 0.f};

  // prologue (vm order: A(0)x4, B(0)x2, A(1)x4, B(1)x2  -> steady vmcnt(10))
  float4 Xa[4], Ya[4];
  #pragma unroll
  for (int i = 0; i < 4; ++i) Xa[i] = *reinterpret_cast<const float4*>(aptr + i*4);
  #pragma unroll
  for (int r = 0; r < 2; ++r) {
    const int p = r*256 + tid;
    const int c = invswz8(p);
    gload_lds16(bbase + (size_t)(c >> 2)*ENC_ + (c & 3)*8, &Bs[0][p*8]);
  }
  #pragma unroll
  for (int i = 0; i < 4; ++i) Ya[i] = *reinterpret_cast<const float4*>(aptr + BK + i*4);
  #pragma unroll
  for (int r = 0; r < 2; ++r) {
    const int p = r*256 + tid;
    const int c = invswz8(p);
    gload_lds16(bbase + (size_t)(c >> 2)*ENC_ + BK + (c & 3)*8, &Bs[1][p*8]);
  }

  int bcur = 0;   // = kt % 3

#define STEP(SA, KT) do {                                                      \
    /* convert & write A(KT) into As[(KT)&1] */                                \
    uint4 pk0, pk1;                                                            \
    pk0.x = cvt2(SA[0].x, SA[0].y);  pk0.y = cvt2(SA[0].z, SA[0].w);           \
    pk0.z = cvt2(SA[1].x, SA[1].y);  pk0.w = cvt2(SA[1].z, SA[1].w);           \
    pk1.x = cvt2(SA[2].x, SA[2].y);  pk1.y = cvt2(SA[2].z, SA[2].w);           \
    pk1.z = cvt2(SA[3].x, SA[3].y);  pk1.w = cvt2(SA[3].z, SA[3].w);           \
    {                                                                          \
      uint4* da = reinterpret_cast<uint4*>(&As[(KT) & 1][arow*LDA + ahalf]);   \
      da[0] = pk0; da[1] = pk1;                                                \
    }                                                                          \
    if ((KT) + 2 < NT) {  /* refill SA with A(KT+2) */                         \
      const float* ap = aptr + ((KT) + 2)*BK;                                  \
      _Pragma("unroll")                                                        \
      for (int i = 0; i < 4; ++i)                                              \
        SA[i] = *reinterpret_cast<const float4*>(ap + i*4);                    \
    }                                                                          \
    /* counted-vmcnt barrier: retires B(KT), keeps A(KT+1),B(KT+1),A(KT+2) */  \
    asm volatile("s_waitcnt vmcnt(10) lgkmcnt(0)" ::: "memory");               \
    __builtin_amdgcn_s_barrier();                                              \
    asm volatile("" ::: "memory");                                             \
    if ((KT) + 2 < NT) {  /* issue B(KT+2) -> Bs[(bcur+2)%3] (no live reader) */\
      unsigned short* bdst = &Bs[bcur >= 1 ? bcur - 1 : 2][0];                 \
      const int k0n = ((KT) + 2)*BK;                                           \
      _Pragma("unroll")                                                        \
      for (int r = 0; r < 2; ++r) {                                            \
        const int p = r*256 + tid;                                             \
        const int c = invswz8(p);                                              \
        gload_lds16(bbase + (size_t)(c >> 2)*ENC_ + k0n + (c & 3)*8, &bdst[p*8]); \
      }                                                                        \
    }                                                                          \
    /* compute tile KT */                                                      \
    {                                                                          \
      const unsigned short* asrc = &As[(KT) & 1][0];                           \
      const unsigned short* bsc  = &Bs[bcur][0];                               \
      short8 aF[4], bF[4];                                                     \
      _Pragma("unroll")                                                        \
      for (int mi = 0; mi < 4; ++mi)                                           \
        aF[mi] = *reinterpret_cast<const short8*>(&asrc[(wm*64 + mi*16 + lrow)*LDA + lk8]); \
      _Pragma("unroll")                                                        \
      for (int ni = 0; ni < 4; ++ni) {                                         \
        const int cr = ((wn*64 + ni*16 + lrow) << 2) + kg;                     \
        const int pr = cr ^ ((cr >> 2) & 7);                                   \
        bF[ni] = *reinterpret_cast<const short8*>(&bsc[pr << 3]);              \
      }                                                                        \
      _Pragma("unroll")                                                        \
      for (int mi = 0; mi < 4; ++mi)                                           \
        _Pragma("unroll")                                                      \
        for (int ni = 0; ni < 4; ++ni)                                         \
          acc[mi][ni] = __builtin_amdgcn_mfma_f32_16x16x32_bf16(               \
              aF[mi], bF[ni], acc[mi][ni], 0, 0, 0);                           \
    }                                                                          \
    bcur = (bcur == 2) ? 0 : bcur + 1;                                         \
  } while (0)

  for (int kt = 0; kt < NT; kt += 2) {
    STEP(Xa, kt);
    STEP(Ya, kt + 1);
  }
#undef STEP

  // ---- epilogue: relu(acc + attn2p) · W_v, reduced over this block's 128 cols
  float wvv[4];
  #pragma unroll
  for (int ni = 0; ni < 4; ++ni) wvv[ni] = Wv[n0 + wn*64 + ni*16 + lrow];
  #pragma unroll
  for (int mi = 0; mi < 4; ++mi) {
    #pragma unroll
    for (int j = 0; j < 4; ++j) {
      const int row_local = wm*64 + mi*16 + g4 + j;
      const int r  = r0 + row_local;
      const int bb = r / HW_;
      const float* a2 = attn2p + (size_t)bb*ATTN_ + n0 + wn*64;
      float s = 0.f;
      #pragma unroll
      for (int ni = 0; ni < 4; ++ni) {
        float v = acc[mi][ni][j] + a2[ni*16 + lrow];
        v = fmaxf(v, 0.f);
        s = fmaf(v, wvv[ni], s);
      }
      s += __shfl_xor(s, 1);
      s += __shfl_xor(s, 2);
      s += __shfl_xor(s, 4);
      s += __shfl_xor(s, 8);
      if (lrow == 0) plog[row_local][wn] = s;
    }
  }
  __syncthreads();
  if (tid < BM)
    partials[(size_t)(r0 + tid)*4 + nb] = plog[tid][0] + plog[tid][1];
}

// ---------------- kernel 4: softmax over s (196) per b
__global__ __launch_bounds__(64)
void k_softmax(const float* __restrict__ partials, const float* __restrict__ bvp,
               float* __restrict__ alpha) {
  const int b = blockIdx.x;
  const int t = threadIdx.x;
  const float bv = bvp[0];
  float lg[4];
  #pragma unroll
  for (int i = 0; i < 4; ++i) {
    const int s = t + i*64;
    if (s < HW_) {
      const float4 p = *reinterpret_cast<const float4*>(&partials[(size_t)(b*HW_ + s)*4]);
      lg[i] = p.x + p.y + p.z + p.w + bv;
    } else lg[i] = -INFINITY;
  }
  float mx = fmaxf(fmaxf(lg[0], lg[1]), fmaxf(lg[2], lg[3]));
  #pragma unroll
  for (int off = 32; off; off >>= 1) mx = fmaxf(mx, __shfl_xor(mx, off));
  float sum = 0.f;
  #pragma unroll
  for (int i = 0; i < 4; ++i) { lg[i] = expf(lg[i] - mx); sum += lg[i]; }
  #pragma unroll
  for (int off = 32; off; off >>= 1) sum += __shfl_xor(sum, off);
  const float inv = 1.0f / sum;
  #pragma unroll
  for (int i = 0; i < 4; ++i) {
    const int s = t + i*64;
    if (s < HW_) alpha[b*HW_ + s] = lg[i] * inv;
  }
}

// ---------------- kernel 5: context[b][e] = sum_s alpha[b][s] * enc[b][s][e]
__global__ __launch_bounds__(256)
void k_context(const float* __restrict__ enc, const float* __restrict__ alpha,
               float* __restrict__ ctx) {
  __shared__ float al[HW_];
  const int bi = blockIdx.x;
  const int b  = bi >> 1;
  const int e0 = (bi & 1) << 10;
  const int t  = threadIdx.x;
  if (t < HW_) al[t] = alpha[b*HW_ + t];
  __syncthreads();
  const float* base = enc + (size_t)b*HW_*ENC_ + e0 + t*4;
  float4 acc = {0.f, 0.f, 0.f, 0.f};
  #pragma unroll 4
  for (int s = 0; s < HW_; ++s) {
    const float a = al[s];
    const float4 v = *reinterpret_cast<const float4*>(base + (size_t)s*ENC_);
    acc.x = fmaf(a, v.x, acc.x);
    acc.y = fmaf(a, v.y, acc.y);
    acc.z = fmaf(a, v.z, acc.z);
    acc.w = fmaf(a, v.w, acc.w);
  }
  *reinterpret_cast<float4*>(&ctx[(size_t)b*ENC_ + e0 + t*4]) = acc;
}

// ---------------- launch
extern "C" void kernel_launch(void* const* d_in, const int* in_sizes, int n_in,
                              void* d_out, int out_size, void* d_ws, size_t ws_size,
                              hipStream_t stream) {
  const float* enc   = (const float*)d_in[0];
  const float* dec_h = (const float*)d_in[1];
  const float* Wenc  = (const float*)d_in[2];
  const float* benc  = (const float*)d_in[3];
  const float* Wdec  = (const float*)d_in[4];
  const float* bdec  = (const float*)d_in[5];
  const float* Wv    = (const float*)d_in[6];
  const float* bv    = (const float*)d_in[7];

  float* ctx   = (float*)d_out;                     // [512][2048]
  float* alpha = (float*)d_out + (size_t)B_*ENC_;   // [512][196]

  char* ws = (char*)d_ws;
  float*          attn2p   = (float*)ws;                          // 1.0 MB
  unsigned short* WencT    = (unsigned short*)(ws + (1u << 20));  // 2.0 MB
  float*          partials = (float*)(ws + 3u*(1u << 20));        // 1.6 MB  [M][4]

  hipLaunchKernelGGL(k_attn2,     dim3(B_),                dim3(256), 0, stream,
                     dec_h, Wdec, bdec, benc, attn2p);
  hipLaunchKernelGGL(k_transpose, dim3(ENC_/32, ATTN_/32), dim3(256), 0, stream,
                     Wenc, WencT);
  hipLaunchKernelGGL(k_gemm_logits, dim3(3136),            dim3(256), 0, stream,
                     enc, WencT, attn2p, Wv, partials);
  hipLaunchKernelGGL(k_softmax,   dim3(B_),                dim3(64),  0, stream,
                     partials, bv, alpha);
  hipLaunchKernelGGL(k_context,   dim3(1024),              dim3(256), 0, stream,
                     enc, alpha, ctx);
}